// Round 14
// baseline (123.921 us; speedup 1.0000x reference)
//
#include <hip/hip_runtime.h>
#include <stdint.h>

#define NB   8
#define NPTS 8192
#define NS   1024
#define NK   16
#define NH   192
#define KP1  224   // extended K for gemm1 weights: 192 + 3 coords + 1 bias + 28 zero pad
#define HROW 196   // hbuf row stride (bf16): 98 dw, gcd(98,32)=2 -> 16-distinct banks/16 rows
#define QTR  2048  // points per knn quarter-block

typedef float    f32x4 __attribute__((ext_vector_type(4)));
typedef short    s16x8 __attribute__((ext_vector_type(8)));
typedef uint32_t u32;
typedef unsigned long long u64;

constexpr float OMEGA[32] = {
  1.0f, 0.74989420933245585f, 0.56234132519034907f, 0.42169650342858223f,
  0.31622776601683794f, 0.23713737056616552f, 0.17782794100389229f, 0.13335214321633237f,
  0.1f, 0.074989420933245585f, 0.056234132519034907f, 0.042169650342858223f,
  0.031622776601683794f, 0.023713737056616552f, 0.017782794100389229f, 0.013335214321633237f,
  0.01f, 0.0074989420933245585f, 0.0056234132519034907f, 0.0042169650342858223f,
  0.0031622776601683794f, 0.0023713737056616552f, 0.0017782794100389229f, 0.0013335214321633237f,
  0.001f, 0.00074989420933245585f, 0.00056234132519034907f, 0.00042169650342858223f,
  0.00031622776601683794f, 0.00023713737056616552f, 0.00017782794100389229f, 0.00013335214321633237f };

__device__ __forceinline__ uint16_t f2bf(float f) {
  u32 u = __float_as_uint(f);
  return (uint16_t)((u + 0x7FFFu + ((u >> 16) & 1u)) >> 16);
}
__device__ __forceinline__ u32 pk2bf(float f0, float f1) {
  return ((__float_as_uint(f0) + 0x8000u) >> 16) |
         ((__float_as_uint(f1) + 0x8000u) & 0xFFFF0000u);
}

// ---------------- kernel A: build extended transposed weights ----------------
__global__ void __launch_bounds__(64) prep_weights(
    const float* __restrict__ w_in, const float* __restrict__ b_in,
    const float* __restrict__ w1, const float* __restrict__ b1,
    const float* __restrict__ w2,
    uint16_t* __restrict__ wT1e, uint16_t* __restrict__ wT2) {
  const int n = blockIdx.x, t = threadIdx.x;
  float p0 = 0, p1 = 0, p2 = 0, pb = 0;
  #pragma unroll
  for (int kk = 0; kk < 3; ++kk) {
    int c = kk * 64 + t;
    float w1cn = w1[c * NH + n];
    wT1e[n * KP1 + c] = f2bf(w1cn);
    wT2 [n * NH  + c] = f2bf(w2[c * NH + n]);
    p0 = fmaf(w_in[0 * NH + c], w1cn, p0);
    p1 = fmaf(w_in[1 * NH + c], w1cn, p1);
    p2 = fmaf(w_in[2 * NH + c], w1cn, p2);
    pb = fmaf(b_in[c], w1cn, pb);
  }
  #pragma unroll
  for (int off = 32; off; off >>= 1) {
    p0 += __shfl_down(p0, off);
    p1 += __shfl_down(p1, off);
    p2 += __shfl_down(p2, off);
    pb += __shfl_down(pb, off);
  }
  if (t == 0) {
    wT1e[n * KP1 + 192] = f2bf(p0);
    wT1e[n * KP1 + 193] = f2bf(p1);
    wT1e[n * KP1 + 194] = f2bf(p2);
    wT1e[n * KP1 + 195] = f2bf(pb + b1[n]);
  }
  if (t >= 4 && t < 32) wT1e[n * KP1 + 192 + t] = 0;
}

// ---------------- kernel B: exact top-16 over a QUARTER ----------------
// r14 single-variable test: drop the (512,8) min-waves bound. r13's VGPR=28 is
// below pass-2's >=36 live registers -> forced spill/remat in the hot loop is
// the prime suspect for the 1.7x instruction inflation that made r11-r13's
// op-count diets all null. Let the allocator pick.
__global__ void __launch_bounds__(512) knn_kernel(const float* __restrict__ pts,
                                                  const int* __restrict__ sidx,
                                                  u64* __restrict__ keys) {
  __shared__ float4 P4[QTR];   // 32 KB
  const int bid = blockIdx.x;
  const int b = bid >> 7;
  const int chunk = (bid >> 2) & 31;
  const int quarter = bid & 3;
  const int pbase = quarter * QTR;
  const float* pb = pts + ((size_t)b * NPTS + pbase) * 3;
  for (int i = threadIdx.x; i < QTR; i += 512)
    P4[i] = float4{pb[3 * i], pb[3 * i + 1], pb[3 * i + 2], 0.0f};
  __syncthreads();
  const int wave = threadIdx.x >> 6, lane = threadIdx.x & 63;
  const int sbase = chunk * 32 + wave * 4;

  float sx[4], sy[4], sz[4], minD[4], Td[4];
  u32 minT[4];
  u64 arr[4], T[4];
  #pragma unroll
  for (int q = 0; q < 4; ++q) {
    int si = sidx[b * NS + sbase + q];
    const float* qp = pts + ((size_t)b * NPTS + si) * 3;   // L2 broadcast
    sx[q] = qp[0]; sy[q] = qp[1]; sz[q] = qp[2];
    minD[q] = __uint_as_float(0x7F800000u);
    minT[q] = 0xFFFFFFFFu;
  }

  // ---- pass 1: lane-private minimum; track iteration number only
  for (int t = 0; t < QTR / 64; ++t) {
    float4 p = P4[t * 64 + lane];
    #pragma unroll
    for (int q = 0; q < 4; ++q) {
      float dx = p.x - sx[q], dy = p.y - sy[q], dz = p.z - sz[q];
      float d = __fadd_rn(__fadd_rn(__fmul_rn(dx, dx), __fmul_rn(dy, dy)),
                          __fmul_rn(dz, dz));
      bool c = d < minD[q];            // strict: keeps lowest idx on exact ties
      minD[q] = c ? d : minD[q];
      minT[q] = c ? (u32)t : minT[q];  // SGPR src -> no per-iter idx add
    }
  }

  // ---- reconstruct keys, bitonic sort of the 64 per-lane minima
  #pragma unroll
  for (int q = 0; q < 4; ++q) {
    u32 gidx = (u32)(pbase + (int)minT[q] * 64 + lane);
    u64 key = ((u64)__float_as_uint(minD[q]) << 32) | gidx;
    #pragma unroll
    for (int k = 2; k <= 64; k <<= 1) {
      #pragma unroll
      for (int jj = k >> 1; jj > 0; jj >>= 1) {
        u64 p = __shfl_xor(key, jj);
        bool takeMin = (((lane & jj) == 0) == ((lane & k) == 0));
        key = (takeMin == (p < key)) ? p : key;
      }
    }
    arr[q] = (lane < 16) ? key : ~0ull;
    T[q] = __shfl(key, 15);                  // upper bound on true 16th key
    Td[q] = __uint_as_float((u32)(T[q] >> 32));
  }

  // ---- pass 2: exact insertion of the few candidates below the threshold
  for (int t = 0; t < QTR / 64; ++t) {
    float4 p = P4[t * 64 + lane];
    #pragma unroll
    for (int q = 0; q < 4; ++q) {
      float dx = p.x - sx[q], dy = p.y - sy[q], dz = p.z - sz[q];
      float d = __fadd_rn(__fadd_rn(__fmul_rn(dx, dx), __fmul_rn(dy, dy)),
                          __fmul_rn(dz, dz));
      // d<=Td superset test; own pass-1 argmin excluded via scalar-t compare
      u64 ball = __ballot(d <= Td[q] && minT[q] != (u32)t);
      if (ball) {                              // wave-uniform, rare
        u64 key = ((u64)__float_as_uint(d) << 32) | (u32)(pbase + t * 64 + lane);
        do {
          int src = __builtin_ctzll(ball);
          ball &= ball - 1;
          u64 k2 = __shfl(key, src);
          if (k2 < T[q]) {                     // exact (dist,idx) compare
            int r = __popcll(__ballot(arr[q] < k2));
            u64 up = __shfl_up(arr[q], 1);
            if (lane == r) arr[q] = k2;
            else if (lane > r && lane < 16) arr[q] = up;
            T[q] = __shfl(arr[q], 15);
            Td[q] = __uint_as_float((u32)(T[q] >> 32));
          }
        } while (ball);
      }
    }
  }
  #pragma unroll
  for (int q = 0; q < 4; ++q)
    if (lane < 16)
      keys[((size_t)(b * NS + sbase + q)) * 64 + quarter * 16 + lane] = arr[q];
}

// ---------------- kernel C: merge + gather + embed + MLP + mean-pool (r12, unchanged) ----
__device__ __forceinline__ float h0ch(int c, float c0, float c1, float c2) {
  int dd = c >> 6, i = c & 63, m = i & 31;
  float coord = (dd == 0) ? c0 : ((dd == 1) ? c1 : c2);
  float arg = coord * OMEGA[m];
  return (i < 32) ? __sinf(arg) : __cosf(arg);
}

__device__ __forceinline__ float gelu_f(float x) {
  float v = -1.5957691216057308f * __fmaf_rn(0.044715f * x, x * x, x);
  return x * __builtin_amdgcn_rcpf(1.0f + __expf(v));
}

__global__ void __launch_bounds__(256, 3) mlp_kernel(
    const float* __restrict__ pts, const u64* __restrict__ keys,
    const float* __restrict__ b2v,
    const uint16_t* __restrict__ wT1e, const uint16_t* __restrict__ wT2,
    float* __restrict__ out) {
  __shared__ uint16_t hbuf[128 * HROW];   // 50.2 KB
  __shared__ float crdL[128][3];          // 1.5 KB (coords per row, for kk6 frag)
  __shared__ int nbrL[128];               // 0.5 KB  -> total 52.2 KB: 3 blocks/CU
  const int g = blockIdx.x, tid = threadIdx.x;
  const int wave = tid >> 6, lane = tid & 63;
  const int lrow = lane & 15, lg = lane >> 4;
  const int ns = wave;                    // n-slice: cols ns*48..+48

  #pragma unroll
  for (int ii = 0; ii < 2; ++ii) { // merge 4 sorted 16-lists for query g*8 + ii*4 + wave
    int q = ii * 4 + wave;
    int list = lane >> 4, pos = lane & 15;
    int rpos = (list & 1) ? (15 - pos) : pos;
    u64 key = keys[((size_t)g * 8 + q) * 64 + list * 16 + rpos];
    #pragma unroll
    for (int jj = 16; jj > 0; jj >>= 1) {
      u64 p = __shfl_xor(key, jj);
      bool takeMin = (((lane & jj) == 0) == ((lane & 32) == 0));
      key = (takeMin == (p < key)) ? p : key;
    }
    #pragma unroll
    for (int jj = 32; jj > 0; jj >>= 1) {
      u64 p = __shfl_xor(key, jj);
      bool takeMin = ((lane & jj) == 0);
      key = (takeMin == (p < key)) ? p : key;
    }
    if (lane < 16) nbrL[q * 16 + lane] = (int)(u32)key;
  }
  __syncthreads();

  { // h0 fill (sincos channels 0..191), 2 threads/row, static half-loops
    int r = tid >> 1, half = tid & 1;
    int grow = g * 128 + r;
    int b = grow >> 14;
    int pidx = nbrL[r];
    const float* pp = pts + ((size_t)b * NPTS + pidx) * 3;
    float c0 = pp[0], c1 = pp[1], c2 = pp[2];
    uint16_t* hrow = hbuf + r * HROW;
    if (half == 0) {
      crdL[r][0] = c0; crdL[r][1] = c1; crdL[r][2] = c2;
      #pragma unroll
      for (int jj = 0; jj < 24; ++jj) {
        const int c = jj * 4;
        uint2 pk;
        pk.x = pk2bf(h0ch(c,     c0, c1, c2), h0ch(c + 1, c0, c1, c2));
        pk.y = pk2bf(h0ch(c + 2, c0, c1, c2), h0ch(c + 3, c0, c1, c2));
        *(uint2*)(hrow + c) = pk;
      }
    } else {
      #pragma unroll
      for (int jj = 0; jj < 24; ++jj) {
        const int c = 96 + jj * 4;
        uint2 pk;
        pk.x = pk2bf(h0ch(c,     c0, c1, c2), h0ch(c + 1, c0, c1, c2));
        pk.y = pk2bf(h0ch(c + 2, c0, c1, c2), h0ch(c + 3, c0, c1, c2));
        *(uint2*)(hrow + c) = pk;
      }
    }
  }
  __syncthreads();

  // ---- gemm1 (SWAPPED operands): D1^T = wT1e-as-A x h0-as-B; kk6 B built in-reg
  f32x4 acc1[3][8] = {};
  {
    const uint16_t* wbase = wT1e + (size_t)(ns * 48 + lrow) * KP1 + lg * 8;
    uint4 anx[2][3];
    #pragma unroll
    for (int nt = 0; nt < 3; ++nt) {
      anx[0][nt] = *(const uint4*)(wbase + nt * 16 * KP1);
      anx[1][nt] = *(const uint4*)(wbase + nt * 16 * KP1 + 32);
    }
    #pragma unroll
    for (int kk = 0; kk < 7; ++kk) {
      uint4 acur[3];
      #pragma unroll
      for (int nt = 0; nt < 3; ++nt) acur[nt] = anx[kk & 1][nt];
      if (kk < 5) {
        #pragma unroll
        for (int nt = 0; nt < 3; ++nt)
          anx[kk & 1][nt] = *(const uint4*)(wbase + nt * 16 * KP1 + (kk + 2) * 32);
      }
      s16x8 bm[8];
      if (kk < 6) {
        #pragma unroll
        for (int mt = 0; mt < 8; ++mt)
          bm[mt] = __builtin_bit_cast(s16x8,
                     *(const uint4*)(hbuf + (mt * 16 + lrow) * HROW + kk * 32 + lg * 8));
      } else {
        // channels 192..223 = [c0,c1,c2,1,0...]: only lanes lg==0 carry data
        #pragma unroll
        for (int mt = 0; mt < 8; ++mt) {
          uint4 t{0, 0, 0, 0};
          if (lg == 0) {
            const float* cp = crdL[mt * 16 + lrow];
            t.x = pk2bf(cp[0], cp[1]);
            t.y = pk2bf(cp[2], 1.0f);
          }
          bm[mt] = __builtin_bit_cast(s16x8, t);
        }
      }
      #pragma unroll
      for (int nt = 0; nt < 3; ++nt)
        #pragma unroll
        for (int mt = 0; mt < 8; ++mt)
          acc1[nt][mt] = __builtin_amdgcn_mfma_f32_16x16x32_bf16(
              __builtin_bit_cast(s16x8, acur[nt]), bm[mt], acc1[nt][mt], 0, 0, 0);
    }
  }
  __syncthreads();   // all gemm1 reads of hbuf done before h1 overwrite

  { // epilogue 1: gelu (b1 folded), h1 write: 4 consecutive cols per b64 store
    #pragma unroll
    for (int nt = 0; nt < 3; ++nt) {
      #pragma unroll
      for (int mt = 0; mt < 8; ++mt) {
        uint2 pk;
        pk.x = pk2bf(gelu_f(acc1[nt][mt][0]), gelu_f(acc1[nt][mt][1]));
        pk.y = pk2bf(gelu_f(acc1[nt][mt][2]), gelu_f(acc1[nt][mt][3]));
        *(uint2*)(hbuf + (mt * 16 + lrow) * HROW + ns * 48 + nt * 16 + lg * 4) = pk;
      }
    }
  }
  __syncthreads();

  // ---- gemm2 (normal orientation): D2 = h1-as-A x wT2-as-B, 2-deep prefetch
  f32x4 acc2[8][3] = {};
  {
    const uint16_t* w2base = wT2 + (size_t)(ns * 48 + lrow) * NH + lg * 8;
    uint4 bnx[2][3];
    #pragma unroll
    for (int nt = 0; nt < 3; ++nt) {
      bnx[0][nt] = *(const uint4*)(w2base + nt * 16 * NH);
      bnx[1][nt] = *(const uint4*)(w2base + nt * 16 * NH + 32);
    }
    #pragma unroll
    for (int kk = 0; kk < 6; ++kk) {
      uint4 bcur[3];
      #pragma unroll
      for (int nt = 0; nt < 3; ++nt) bcur[nt] = bnx[kk & 1][nt];
      if (kk < 4) {
        #pragma unroll
        for (int nt = 0; nt < 3; ++nt)
          bnx[kk & 1][nt] = *(const uint4*)(w2base + nt * 16 * NH + (kk + 2) * 32);
      }
      s16x8 am[8];
      #pragma unroll
      for (int mt = 0; mt < 8; ++mt)
        am[mt] = __builtin_bit_cast(s16x8,
                   *(const uint4*)(hbuf + (mt * 16 + lrow) * HROW + kk * 32 + lg * 8));
      #pragma unroll
      for (int mt = 0; mt < 8; ++mt)
        #pragma unroll
        for (int nt = 0; nt < 3; ++nt)
          acc2[mt][nt] = __builtin_amdgcn_mfma_f32_16x16x32_bf16(
              am[mt], __builtin_bit_cast(s16x8, bcur[nt]), acc2[mt][nt], 0, 0, 0);
    }
  }

  { // epilogue 2: mean over 16 rows of each C-tile (one supernode) + b2
    #pragma unroll
    for (int mt = 0; mt < 8; ++mt) {
      #pragma unroll
      for (int nt = 0; nt < 3; ++nt) {
        float ssum = acc2[mt][nt][0] + acc2[mt][nt][1] + acc2[mt][nt][2] + acc2[mt][nt][3];
        ssum += __shfl_xor(ssum, 16);
        ssum += __shfl_xor(ssum, 32);
        if (lane < 16) {
          int col = ns * 48 + nt * 16 + lrow;
          out[(size_t)(g * 8 + mt) * NH + col] = ssum * 0.0625f + b2v[col];
        }
      }
    }
  }
}

extern "C" void kernel_launch(void* const* d_in, const int* in_sizes, int n_in,
                              void* d_out, int out_size, void* d_ws, size_t ws_size,
                              hipStream_t stream) {
  (void)in_sizes; (void)n_in; (void)out_size; (void)ws_size;
  const float* pts  = (const float*)d_in[0];
  const int*   sidx = (const int*)d_in[1];
  const float* w_in = (const float*)d_in[2];
  const float* b_in = (const float*)d_in[3];
  const float* w1   = (const float*)d_in[4];
  const float* b1   = (const float*)d_in[5];
  const float* w2   = (const float*)d_in[6];
  const float* b2   = (const float*)d_in[7];
  float* out = (float*)d_out;

  u64* keys = (u64*)d_ws;                                       // 8192*64*8 = 4 MB
  uint16_t* wT1e = (uint16_t*)((char*)d_ws + (size_t)NB * NS * 64 * 8);
  uint16_t* wT2  = wT1e + NH * KP1;

  hipLaunchKernelGGL(prep_weights, dim3(NH), dim3(64), 0, stream,
                     w_in, b_in, w1, b1, w2, wT1e, wT2);

  hipLaunchKernelGGL(knn_kernel, dim3(NB * 128), dim3(512), 0, stream,
                     pts, sidx, keys);

  hipLaunchKernelGGL(mlp_kernel, dim3(NB * NS / 8), dim3(256), 0, stream,
                     pts, keys, b2, wT1e, wT2, out);
}

// Round 15
// 92.613 us; speedup vs baseline: 1.3381x; 1.3381x over previous
//
#include <hip/hip_runtime.h>
#include <stdint.h>

#define NB   8
#define NPTS 8192
#define NS   1024
#define NK   16
#define NH   192
#define KP1  224   // extended K for gemm1 weights: 192 + 3 coords + 1 bias + 28 zero pad
#define HROW 196   // hbuf row stride (bf16): 98 dw, gcd(98,32)=2 -> 16-distinct banks/16 rows
#define QTR  2048  // points per knn quarter-block

typedef float    f32x4 __attribute__((ext_vector_type(4)));
typedef short    s16x8 __attribute__((ext_vector_type(8)));
typedef uint32_t u32;
typedef unsigned long long u64;

constexpr float OMEGA[32] = {
  1.0f, 0.74989420933245585f, 0.56234132519034907f, 0.42169650342858223f,
  0.31622776601683794f, 0.23713737056616552f, 0.17782794100389229f, 0.13335214321633237f,
  0.1f, 0.074989420933245585f, 0.056234132519034907f, 0.042169650342858223f,
  0.031622776601683794f, 0.023713737056616552f, 0.017782794100389229f, 0.013335214321633237f,
  0.01f, 0.0074989420933245585f, 0.0056234132519034907f, 0.0042169650342858223f,
  0.0031622776601683794f, 0.0023713737056616552f, 0.0017782794100389229f, 0.0013335214321633237f,
  0.001f, 0.00074989420933245585f, 0.00056234132519034907f, 0.00042169650342858223f,
  0.00031622776601683794f, 0.00023713737056616552f, 0.00017782794100389229f, 0.00013335214321633237f };

__device__ __forceinline__ uint16_t f2bf(float f) {
  u32 u = __float_as_uint(f);
  return (uint16_t)((u + 0x7FFFu + ((u >> 16) & 1u)) >> 16);
}
__device__ __forceinline__ u32 pk2bf(float f0, float f1) {
  return ((__float_as_uint(f0) + 0x8000u) >> 16) |
         ((__float_as_uint(f1) + 0x8000u) & 0xFFFF0000u);
}
// wave-uniform hints -> SGPR allocation (values are already uniform; no-op semantically)
__device__ __forceinline__ float rflf(float v) {
  return __uint_as_float(__builtin_amdgcn_readfirstlane(__float_as_uint(v)));
}
__device__ __forceinline__ u64 rfl64(u64 v) {
  u32 lo = __builtin_amdgcn_readfirstlane((u32)v);
  u32 hi = __builtin_amdgcn_readfirstlane((u32)(v >> 32));
  return ((u64)hi << 32) | lo;
}

// ---------------- kernel A: build extended transposed weights ----------------
__global__ void __launch_bounds__(64) prep_weights(
    const float* __restrict__ w_in, const float* __restrict__ b_in,
    const float* __restrict__ w1, const float* __restrict__ b1,
    const float* __restrict__ w2,
    uint16_t* __restrict__ wT1e, uint16_t* __restrict__ wT2) {
  const int n = blockIdx.x, t = threadIdx.x;
  float p0 = 0, p1 = 0, p2 = 0, pb = 0;
  #pragma unroll
  for (int kk = 0; kk < 3; ++kk) {
    int c = kk * 64 + t;
    float w1cn = w1[c * NH + n];
    wT1e[n * KP1 + c] = f2bf(w1cn);
    wT2 [n * NH  + c] = f2bf(w2[c * NH + n]);
    p0 = fmaf(w_in[0 * NH + c], w1cn, p0);
    p1 = fmaf(w_in[1 * NH + c], w1cn, p1);
    p2 = fmaf(w_in[2 * NH + c], w1cn, p2);
    pb = fmaf(b_in[c], w1cn, pb);
  }
  #pragma unroll
  for (int off = 32; off; off >>= 1) {
    p0 += __shfl_down(p0, off);
    p1 += __shfl_down(p1, off);
    p2 += __shfl_down(p2, off);
    pb += __shfl_down(pb, off);
  }
  if (t == 0) {
    wT1e[n * KP1 + 192] = f2bf(p0);
    wT1e[n * KP1 + 193] = f2bf(p1);
    wT1e[n * KP1 + 194] = f2bf(p2);
    wT1e[n * KP1 + 195] = f2bf(pb + b1[n]);
  }
  if (t >= 4 && t < 32) wT1e[n * KP1 + 192 + t] = 0;
}

// ---------------- kernel B: exact top-16 over a QUARTER ----------------
// r14 falsified "free the allocator" (100 VGPR, 2.5 waves, 85us). r15: keep
// (512,8) TLP and remove the uniform-value register pressure instead:
// sx/sy/sz and T/Td are wave-uniform -> readfirstlane pins them to SGPRs,
// cutting per-lane live VGPRs to ~22 (fits 8-wave cap without remat/spill).
__global__ void __launch_bounds__(512, 8) knn_kernel(const float* __restrict__ pts,
                                                     const int* __restrict__ sidx,
                                                     u64* __restrict__ keys) {
  __shared__ float4 P4[QTR];   // 32 KB
  const int bid = blockIdx.x;
  const int b = bid >> 7;
  const int chunk = (bid >> 2) & 31;
  const int quarter = bid & 3;
  const int pbase = quarter * QTR;
  const float* pb = pts + ((size_t)b * NPTS + pbase) * 3;
  for (int i = threadIdx.x; i < QTR; i += 512)
    P4[i] = float4{pb[3 * i], pb[3 * i + 1], pb[3 * i + 2], 0.0f};
  __syncthreads();
  const int wave = threadIdx.x >> 6, lane = threadIdx.x & 63;
  const int sbase = chunk * 32 + wave * 4;

  float sx[4], sy[4], sz[4], minD[4], Td[4];
  u32 minT[4];
  u64 arr[4], T[4];
  #pragma unroll
  for (int q = 0; q < 4; ++q) {
    int si = __builtin_amdgcn_readfirstlane(sidx[b * NS + sbase + q]);
    const float* qp = pts + ((size_t)b * NPTS + si) * 3;   // uniform address
    sx[q] = rflf(qp[0]); sy[q] = rflf(qp[1]); sz[q] = rflf(qp[2]);  // SGPRs
    minD[q] = __uint_as_float(0x7F800000u);
    minT[q] = 0xFFFFFFFFu;
  }

  // ---- pass 1: lane-private minimum; track iteration number only
  for (int t = 0; t < QTR / 64; ++t) {
    float4 p = P4[t * 64 + lane];
    #pragma unroll
    for (int q = 0; q < 4; ++q) {
      float dx = p.x - sx[q], dy = p.y - sy[q], dz = p.z - sz[q];
      float d = __fadd_rn(__fadd_rn(__fmul_rn(dx, dx), __fmul_rn(dy, dy)),
                          __fmul_rn(dz, dz));
      bool c = d < minD[q];            // strict: keeps lowest idx on exact ties
      minD[q] = c ? d : minD[q];
      minT[q] = c ? (u32)t : minT[q];
    }
  }

  // ---- reconstruct keys, bitonic sort of the 64 per-lane minima
  #pragma unroll
  for (int q = 0; q < 4; ++q) {
    u32 gidx = (u32)(pbase + (int)minT[q] * 64 + lane);
    u64 key = ((u64)__float_as_uint(minD[q]) << 32) | gidx;
    #pragma unroll
    for (int k = 2; k <= 64; k <<= 1) {
      #pragma unroll
      for (int jj = k >> 1; jj > 0; jj >>= 1) {
        u64 p = __shfl_xor(key, jj);
        bool takeMin = (((lane & jj) == 0) == ((lane & k) == 0));
        key = (takeMin == (p < key)) ? p : key;
      }
    }
    arr[q] = (lane < 16) ? key : ~0ull;
    T[q] = rfl64(__shfl(key, 15));           // SGPR pair: upper bound on 16th key
    Td[q] = __uint_as_float((u32)(T[q] >> 32));
  }

  // ---- pass 2: exact insertion of the few candidates below the threshold
  for (int t = 0; t < QTR / 64; ++t) {
    float4 p = P4[t * 64 + lane];
    #pragma unroll
    for (int q = 0; q < 4; ++q) {
      float dx = p.x - sx[q], dy = p.y - sy[q], dz = p.z - sz[q];
      float d = __fadd_rn(__fadd_rn(__fmul_rn(dx, dx), __fmul_rn(dy, dy)),
                          __fmul_rn(dz, dz));
      // d<=Td superset test; own pass-1 argmin excluded via scalar-t compare
      u64 ball = __ballot(d <= Td[q] && minT[q] != (u32)t);
      if (ball) {                              // wave-uniform, rare
        u64 key = ((u64)__float_as_uint(d) << 32) | (u32)(pbase + t * 64 + lane);
        do {
          int src = __builtin_ctzll(ball);
          ball &= ball - 1;
          u64 k2 = rfl64(__shfl(key, src));
          if (k2 < T[q]) {                     // exact (dist,idx) compare, uniform
            int r = __popcll(__ballot(arr[q] < k2));
            u64 up = __shfl_up(arr[q], 1);
            if (lane == r) arr[q] = k2;
            else if (lane > r && lane < 16) arr[q] = up;
            T[q] = rfl64(__shfl(arr[q], 15));
            Td[q] = __uint_as_float((u32)(T[q] >> 32));
          }
        } while (ball);
      }
    }
  }
  #pragma unroll
  for (int q = 0; q < 4; ++q)
    if (lane < 16)
      keys[((size_t)(b * NS + sbase + q)) * 64 + quarter * 16 + lane] = arr[q];
}

// ---------------- kernel C: merge + gather + embed + MLP + mean-pool (r12, unchanged) ----
__device__ __forceinline__ float h0ch(int c, float c0, float c1, float c2) {
  int dd = c >> 6, i = c & 63, m = i & 31;
  float coord = (dd == 0) ? c0 : ((dd == 1) ? c1 : c2);
  float arg = coord * OMEGA[m];
  return (i < 32) ? __sinf(arg) : __cosf(arg);
}

__device__ __forceinline__ float gelu_f(float x) {
  float v = -1.5957691216057308f * __fmaf_rn(0.044715f * x, x * x, x);
  return x * __builtin_amdgcn_rcpf(1.0f + __expf(v));
}

__global__ void __launch_bounds__(256, 3) mlp_kernel(
    const float* __restrict__ pts, const u64* __restrict__ keys,
    const float* __restrict__ b2v,
    const uint16_t* __restrict__ wT1e, const uint16_t* __restrict__ wT2,
    float* __restrict__ out) {
  __shared__ uint16_t hbuf[128 * HROW];   // 50.2 KB
  __shared__ float crdL[128][3];          // 1.5 KB (coords per row, for kk6 frag)
  __shared__ int nbrL[128];               // 0.5 KB  -> total 52.2 KB: 3 blocks/CU
  const int g = blockIdx.x, tid = threadIdx.x;
  const int wave = tid >> 6, lane = tid & 63;
  const int lrow = lane & 15, lg = lane >> 4;
  const int ns = wave;                    // n-slice: cols ns*48..+48

  #pragma unroll
  for (int ii = 0; ii < 2; ++ii) { // merge 4 sorted 16-lists for query g*8 + ii*4 + wave
    int q = ii * 4 + wave;
    int list = lane >> 4, pos = lane & 15;
    int rpos = (list & 1) ? (15 - pos) : pos;
    u64 key = keys[((size_t)g * 8 + q) * 64 + list * 16 + rpos];
    #pragma unroll
    for (int jj = 16; jj > 0; jj >>= 1) {
      u64 p = __shfl_xor(key, jj);
      bool takeMin = (((lane & jj) == 0) == ((lane & 32) == 0));
      key = (takeMin == (p < key)) ? p : key;
    }
    #pragma unroll
    for (int jj = 32; jj > 0; jj >>= 1) {
      u64 p = __shfl_xor(key, jj);
      bool takeMin = ((lane & jj) == 0);
      key = (takeMin == (p < key)) ? p : key;
    }
    if (lane < 16) nbrL[q * 16 + lane] = (int)(u32)key;
  }
  __syncthreads();

  { // h0 fill (sincos channels 0..191), 2 threads/row, static half-loops
    int r = tid >> 1, half = tid & 1;
    int grow = g * 128 + r;
    int b = grow >> 14;
    int pidx = nbrL[r];
    const float* pp = pts + ((size_t)b * NPTS + pidx) * 3;
    float c0 = pp[0], c1 = pp[1], c2 = pp[2];
    uint16_t* hrow = hbuf + r * HROW;
    if (half == 0) {
      crdL[r][0] = c0; crdL[r][1] = c1; crdL[r][2] = c2;
      #pragma unroll
      for (int jj = 0; jj < 24; ++jj) {
        const int c = jj * 4;
        uint2 pk;
        pk.x = pk2bf(h0ch(c,     c0, c1, c2), h0ch(c + 1, c0, c1, c2));
        pk.y = pk2bf(h0ch(c + 2, c0, c1, c2), h0ch(c + 3, c0, c1, c2));
        *(uint2*)(hrow + c) = pk;
      }
    } else {
      #pragma unroll
      for (int jj = 0; jj < 24; ++jj) {
        const int c = 96 + jj * 4;
        uint2 pk;
        pk.x = pk2bf(h0ch(c,     c0, c1, c2), h0ch(c + 1, c0, c1, c2));
        pk.y = pk2bf(h0ch(c + 2, c0, c1, c2), h0ch(c + 3, c0, c1, c2));
        *(uint2*)(hrow + c) = pk;
      }
    }
  }
  __syncthreads();

  // ---- gemm1 (SWAPPED operands): D1^T = wT1e-as-A x h0-as-B; kk6 B built in-reg
  f32x4 acc1[3][8] = {};
  {
    const uint16_t* wbase = wT1e + (size_t)(ns * 48 + lrow) * KP1 + lg * 8;
    uint4 anx[2][3];
    #pragma unroll
    for (int nt = 0; nt < 3; ++nt) {
      anx[0][nt] = *(const uint4*)(wbase + nt * 16 * KP1);
      anx[1][nt] = *(const uint4*)(wbase + nt * 16 * KP1 + 32);
    }
    #pragma unroll
    for (int kk = 0; kk < 7; ++kk) {
      uint4 acur[3];
      #pragma unroll
      for (int nt = 0; nt < 3; ++nt) acur[nt] = anx[kk & 1][nt];
      if (kk < 5) {
        #pragma unroll
        for (int nt = 0; nt < 3; ++nt)
          anx[kk & 1][nt] = *(const uint4*)(wbase + nt * 16 * KP1 + (kk + 2) * 32);
      }
      s16x8 bm[8];
      if (kk < 6) {
        #pragma unroll
        for (int mt = 0; mt < 8; ++mt)
          bm[mt] = __builtin_bit_cast(s16x8,
                     *(const uint4*)(hbuf + (mt * 16 + lrow) * HROW + kk * 32 + lg * 8));
      } else {
        // channels 192..223 = [c0,c1,c2,1,0...]: only lanes lg==0 carry data
        #pragma unroll
        for (int mt = 0; mt < 8; ++mt) {
          uint4 t{0, 0, 0, 0};
          if (lg == 0) {
            const float* cp = crdL[mt * 16 + lrow];
            t.x = pk2bf(cp[0], cp[1]);
            t.y = pk2bf(cp[2], 1.0f);
          }
          bm[mt] = __builtin_bit_cast(s16x8, t);
        }
      }
      #pragma unroll
      for (int nt = 0; nt < 3; ++nt)
        #pragma unroll
        for (int mt = 0; mt < 8; ++mt)
          acc1[nt][mt] = __builtin_amdgcn_mfma_f32_16x16x32_bf16(
              __builtin_bit_cast(s16x8, acur[nt]), bm[mt], acc1[nt][mt], 0, 0, 0);
    }
  }
  __syncthreads();   // all gemm1 reads of hbuf done before h1 overwrite

  { // epilogue 1: gelu (b1 folded), h1 write: 4 consecutive cols per b64 store
    #pragma unroll
    for (int nt = 0; nt < 3; ++nt) {
      #pragma unroll
      for (int mt = 0; mt < 8; ++mt) {
        uint2 pk;
        pk.x = pk2bf(gelu_f(acc1[nt][mt][0]), gelu_f(acc1[nt][mt][1]));
        pk.y = pk2bf(gelu_f(acc1[nt][mt][2]), gelu_f(acc1[nt][mt][3]));
        *(uint2*)(hbuf + (mt * 16 + lrow) * HROW + ns * 48 + nt * 16 + lg * 4) = pk;
      }
    }
  }
  __syncthreads();

  // ---- gemm2 (normal orientation): D2 = h1-as-A x wT2-as-B, 2-deep prefetch
  f32x4 acc2[8][3] = {};
  {
    const uint16_t* w2base = wT2 + (size_t)(ns * 48 + lrow) * NH + lg * 8;
    uint4 bnx[2][3];
    #pragma unroll
    for (int nt = 0; nt < 3; ++nt) {
      bnx[0][nt] = *(const uint4*)(w2base + nt * 16 * NH);
      bnx[1][nt] = *(const uint4*)(w2base + nt * 16 * NH + 32);
    }
    #pragma unroll
    for (int kk = 0; kk < 6; ++kk) {
      uint4 bcur[3];
      #pragma unroll
      for (int nt = 0; nt < 3; ++nt) bcur[nt] = bnx[kk & 1][nt];
      if (kk < 4) {
        #pragma unroll
        for (int nt = 0; nt < 3; ++nt)
          bnx[kk & 1][nt] = *(const uint4*)(w2base + nt * 16 * NH + (kk + 2) * 32);
      }
      s16x8 am[8];
      #pragma unroll
      for (int mt = 0; mt < 8; ++mt)
        am[mt] = __builtin_bit_cast(s16x8,
                   *(const uint4*)(hbuf + (mt * 16 + lrow) * HROW + kk * 32 + lg * 8));
      #pragma unroll
      for (int mt = 0; mt < 8; ++mt)
        #pragma unroll
        for (int nt = 0; nt < 3; ++nt)
          acc2[mt][nt] = __builtin_amdgcn_mfma_f32_16x16x32_bf16(
              am[mt], __builtin_bit_cast(s16x8, bcur[nt]), acc2[mt][nt], 0, 0, 0);
    }
  }

  { // epilogue 2: mean over 16 rows of each C-tile (one supernode) + b2
    #pragma unroll
    for (int mt = 0; mt < 8; ++mt) {
      #pragma unroll
      for (int nt = 0; nt < 3; ++nt) {
        float ssum = acc2[mt][nt][0] + acc2[mt][nt][1] + acc2[mt][nt][2] + acc2[mt][nt][3];
        ssum += __shfl_xor(ssum, 16);
        ssum += __shfl_xor(ssum, 32);
        if (lane < 16) {
          int col = ns * 48 + nt * 16 + lrow;
          out[(size_t)(g * 8 + mt) * NH + col] = ssum * 0.0625f + b2v[col];
        }
      }
    }
  }
}

extern "C" void kernel_launch(void* const* d_in, const int* in_sizes, int n_in,
                              void* d_out, int out_size, void* d_ws, size_t ws_size,
                              hipStream_t stream) {
  (void)in_sizes; (void)n_in; (void)out_size; (void)ws_size;
  const float* pts  = (const float*)d_in[0];
  const int*   sidx = (const int*)d_in[1];
  const float* w_in = (const float*)d_in[2];
  const float* b_in = (const float*)d_in[3];
  const float* w1   = (const float*)d_in[4];
  const float* b1   = (const float*)d_in[5];
  const float* w2   = (const float*)d_in[6];
  const float* b2   = (const float*)d_in[7];
  float* out = (float*)d_out;

  u64* keys = (u64*)d_ws;                                       // 8192*64*8 = 4 MB
  uint16_t* wT1e = (uint16_t*)((char*)d_ws + (size_t)NB * NS * 64 * 8);
  uint16_t* wT2  = wT1e + NH * KP1;

  hipLaunchKernelGGL(prep_weights, dim3(NH), dim3(64), 0, stream,
                     w_in, b_in, w1, b1, w2, wT1e, wT2);

  hipLaunchKernelGGL(knn_kernel, dim3(NB * 128), dim3(512), 0, stream,
                     pts, sidx, keys);

  hipLaunchKernelGGL(mlp_kernel, dim3(NB * NS / 8), dim3(256), 0, stream,
                     pts, keys, b2, wT1e, wT2, out);
}

// Round 16
// 92.211 us; speedup vs baseline: 1.3439x; 1.0044x over previous
//
#include <hip/hip_runtime.h>
#include <stdint.h>

#define NB   8
#define NPTS 8192
#define NS   1024
#define NK   16
#define NH   192
#define KP1  224   // extended K for gemm1 weights: 192 + 3 coords + 1 bias + 28 zero pad
#define HROW 196   // hbuf row stride (bf16): 98 dw, gcd(98,32)=2 -> 16-distinct banks/16 rows
#define QTR  2048  // points per knn quarter-block

typedef float    f32x4 __attribute__((ext_vector_type(4)));
typedef short    s16x8 __attribute__((ext_vector_type(8)));
typedef uint32_t u32;
typedef unsigned long long u64;

constexpr float OMEGA[32] = {
  1.0f, 0.74989420933245585f, 0.56234132519034907f, 0.42169650342858223f,
  0.31622776601683794f, 0.23713737056616552f, 0.17782794100389229f, 0.13335214321633237f,
  0.1f, 0.074989420933245585f, 0.056234132519034907f, 0.042169650342858223f,
  0.031622776601683794f, 0.023713737056616552f, 0.017782794100389229f, 0.013335214321633237f,
  0.01f, 0.0074989420933245585f, 0.0056234132519034907f, 0.0042169650342858223f,
  0.0031622776601683794f, 0.0023713737056616552f, 0.0017782794100389229f, 0.0013335214321633237f,
  0.001f, 0.00074989420933245585f, 0.00056234132519034907f, 0.00042169650342858223f,
  0.00031622776601683794f, 0.00023713737056616552f, 0.00017782794100389229f, 0.00013335214321633237f };

__device__ __forceinline__ uint16_t f2bf(float f) {
  u32 u = __float_as_uint(f);
  return (uint16_t)((u + 0x7FFFu + ((u >> 16) & 1u)) >> 16);
}
__device__ __forceinline__ u32 pk2bf(float f0, float f1) {
  return ((__float_as_uint(f0) + 0x8000u) >> 16) |
         ((__float_as_uint(f1) + 0x8000u) & 0xFFFF0000u);
}
__device__ __forceinline__ float rflf(float v) {
  return __uint_as_float(__builtin_amdgcn_readfirstlane(__float_as_uint(v)));
}
__device__ __forceinline__ u64 rfl64(u64 v) {
  u32 lo = __builtin_amdgcn_readfirstlane((u32)v);
  u32 hi = __builtin_amdgcn_readfirstlane((u32)(v >> 32));
  return ((u64)hi << 32) | lo;
}

// ---------------- kernel A: build extended transposed weights ----------------
__global__ void __launch_bounds__(64) prep_weights(
    const float* __restrict__ w_in, const float* __restrict__ b_in,
    const float* __restrict__ w1, const float* __restrict__ b1,
    const float* __restrict__ w2,
    uint16_t* __restrict__ wT1e, uint16_t* __restrict__ wT2) {
  const int n = blockIdx.x, t = threadIdx.x;
  float p0 = 0, p1 = 0, p2 = 0, pb = 0;
  #pragma unroll
  for (int kk = 0; kk < 3; ++kk) {
    int c = kk * 64 + t;
    float w1cn = w1[c * NH + n];
    wT1e[n * KP1 + c] = f2bf(w1cn);
    wT2 [n * NH  + c] = f2bf(w2[c * NH + n]);
    p0 = fmaf(w_in[0 * NH + c], w1cn, p0);
    p1 = fmaf(w_in[1 * NH + c], w1cn, p1);
    p2 = fmaf(w_in[2 * NH + c], w1cn, p2);
    pb = fmaf(b_in[c], w1cn, pb);
  }
  #pragma unroll
  for (int off = 32; off; off >>= 1) {
    p0 += __shfl_down(p0, off);
    p1 += __shfl_down(p1, off);
    p2 += __shfl_down(p2, off);
    pb += __shfl_down(pb, off);
  }
  if (t == 0) {
    wT1e[n * KP1 + 192] = f2bf(p0);
    wT1e[n * KP1 + 193] = f2bf(p1);
    wT1e[n * KP1 + 194] = f2bf(p2);
    wT1e[n * KP1 + 195] = f2bf(pb + b1[n]);
  }
  if (t >= 4 && t < 32) wT1e[n * KP1 + 192 + t] = 0;
}

// ---------------- kernel B: exact top-16, SINGLE-PASS top-2 + flagged repair ----------------
// r12-r15 lesson: the two-scan structure pins knn at ~51us regardless of per-pair
// op diets. This removes one full scan. Each lane tracks its column's TWO smallest
// exact keys (min via fminf, 2nd via med3 = fminf(fmaxf(d,m1),m2); strict compares
// keep lowest idx on ties). Sort min1-keys -> arr,T. Insert min2-keys < T (few).
// Completeness: a missed candidate is rank>=3 in its column => key > column min2key;
// columns with min2key < T (expected ~2/query) are rescanned cooperatively with
// exact keys. T only tightens -> all tests conservative. Keys bit-identical.
__global__ void __launch_bounds__(512, 8) knn_kernel(const float* __restrict__ pts,
                                                     const int* __restrict__ sidx,
                                                     u64* __restrict__ keys) {
  __shared__ float4 P4[QTR];   // 32 KB
  const int bid = blockIdx.x;
  const int b = bid >> 7;
  const int chunk = (bid >> 2) & 31;
  const int quarter = bid & 3;
  const int pbase = quarter * QTR;
  const float* pb = pts + ((size_t)b * NPTS + pbase) * 3;
  for (int i = threadIdx.x; i < QTR; i += 512)
    P4[i] = float4{pb[3 * i], pb[3 * i + 1], pb[3 * i + 2], 0.0f};
  __syncthreads();
  const int wave = threadIdx.x >> 6, lane = threadIdx.x & 63;
  const int sbase = chunk * 32 + wave * 4;

  float sx[4], sy[4], sz[4], Td[4];
  float m1D[4], m2D[4];
  u32 m1T[4], m2T[4];
  u64 arr[4], T[4];
  #pragma unroll
  for (int q = 0; q < 4; ++q) {
    int si = __builtin_amdgcn_readfirstlane(sidx[b * NS + sbase + q]);
    const float* qp = pts + ((size_t)b * NPTS + si) * 3;   // uniform address
    sx[q] = rflf(qp[0]); sy[q] = rflf(qp[1]); sz[q] = rflf(qp[2]);  // SGPRs
    m1D[q] = __uint_as_float(0x7F800000u);
    m2D[q] = __uint_as_float(0x7F800000u);
    m1T[q] = 0xFFFFFFFFu; m2T[q] = 0xFFFFFFFFu;
  }

  // ---- single pass: per-lane exact top-2 of the lane's 32-candidate column
  for (int t = 0; t < QTR / 64; ++t) {
    float4 p = P4[t * 64 + lane];
    #pragma unroll
    for (int q = 0; q < 4; ++q) {
      float dx = p.x - sx[q], dy = p.y - sy[q], dz = p.z - sz[q];
      float d = __fadd_rn(__fadd_rn(__fmul_rn(dx, dx), __fmul_rn(dy, dy)),
                          __fmul_rn(dz, dz));
      bool c1 = d < m1D[q];                      // strict: lowest idx on ties
      bool c2 = d < m2D[q];
      m2D[q] = fminf(fmaxf(d, m1D[q]), m2D[q]);  // med3(d,m1,m2) = new 2nd-min
      m2T[q] = c2 ? (c1 ? m1T[q] : (u32)t) : m2T[q];
      m1D[q] = fminf(d, m1D[q]);
      m1T[q] = c1 ? (u32)t : m1T[q];
    }
  }

  // ---- per query: sort min1-keys; insert min2-keys; repair flagged columns
  #pragma unroll
  for (int q = 0; q < 4; ++q) {
    u64 key = ((u64)__float_as_uint(m1D[q]) << 32)
            | (u32)(pbase + (int)m1T[q] * 64 + lane);
    #pragma unroll
    for (int k = 2; k <= 64; k <<= 1) {
      #pragma unroll
      for (int jj = k >> 1; jj > 0; jj >>= 1) {
        u64 p = __shfl_xor(key, jj);
        bool takeMin = (((lane & jj) == 0) == ((lane & k) == 0));
        key = (takeMin == (p < key)) ? p : key;
      }
    }
    arr[q] = (lane < 16) ? key : ~0ull;
    T[q] = rfl64(__shfl(key, 15));
    Td[q] = __uint_as_float((u32)(T[q] >> 32));
    (void)Td;

    // insert the min2 candidates that beat the threshold
    u64 key2 = ((u64)__float_as_uint(m2D[q]) << 32)
             | (u32)(pbase + (int)m2T[q] * 64 + lane);
    u64 ball = __ballot(key2 < T[q]);
    while (ball) {
      int src = __builtin_ctzll(ball);
      ball &= ball - 1;
      u64 k2 = rfl64(__shfl(key2, src));
      if (k2 < T[q]) {                           // recheck: T tightens
        int r = __popcll(__ballot(arr[q] < k2));
        u64 up = __shfl_up(arr[q], 1);
        if (lane == r) arr[q] = k2;
        else if (lane > r && lane < 16) arr[q] = up;
        T[q] = rfl64(__shfl(arr[q], 15));
      }
    }

    // columns whose min2-key is still below T may hide a rank>=3 member
    u64 flags = __ballot(key2 < T[q]);
    while (flags) {
      int j = __builtin_ctzll(flags);
      flags &= flags - 1;
      u32 ex1 = __builtin_amdgcn_readfirstlane(__shfl(m1T[q], j));
      u32 ex2 = __builtin_amdgcn_readfirstlane(__shfl(m2T[q], j));
      u64 ckey = ~0ull;
      if (lane < QTR / 64) {                     // lane = candidate t in column j
        float4 p = P4[lane * 64 + j];
        float dx = p.x - sx[q], dy = p.y - sy[q], dz = p.z - sz[q];
        float d = __fadd_rn(__fadd_rn(__fmul_rn(dx, dx), __fmul_rn(dy, dy)),
                            __fmul_rn(dz, dz));
        ckey = ((u64)__float_as_uint(d) << 32) | (u32)(pbase + lane * 64 + j);
        if ((u32)lane == ex1 || (u32)lane == ex2) ckey = ~0ull;  // already handled
      }
      u64 b2 = __ballot(ckey < T[q]);
      while (b2) {
        int src = __builtin_ctzll(b2);
        b2 &= b2 - 1;
        u64 k2 = rfl64(__shfl(ckey, src));
        if (k2 < T[q]) {
          int r = __popcll(__ballot(arr[q] < k2));
          u64 up = __shfl_up(arr[q], 1);
          if (lane == r) arr[q] = k2;
          else if (lane > r && lane < 16) arr[q] = up;
          T[q] = rfl64(__shfl(arr[q], 15));
        }
      }
    }
  }
  #pragma unroll
  for (int q = 0; q < 4; ++q)
    if (lane < 16)
      keys[((size_t)(b * NS + sbase + q)) * 64 + quarter * 16 + lane] = arr[q];
}

// ---------------- kernel C: merge + gather + embed + MLP + mean-pool (r12, unchanged) ----
__device__ __forceinline__ float h0ch(int c, float c0, float c1, float c2) {
  int dd = c >> 6, i = c & 63, m = i & 31;
  float coord = (dd == 0) ? c0 : ((dd == 1) ? c1 : c2);
  float arg = coord * OMEGA[m];
  return (i < 32) ? __sinf(arg) : __cosf(arg);
}

__device__ __forceinline__ float gelu_f(float x) {
  float v = -1.5957691216057308f * __fmaf_rn(0.044715f * x, x * x, x);
  return x * __builtin_amdgcn_rcpf(1.0f + __expf(v));
}

__global__ void __launch_bounds__(256, 3) mlp_kernel(
    const float* __restrict__ pts, const u64* __restrict__ keys,
    const float* __restrict__ b2v,
    const uint16_t* __restrict__ wT1e, const uint16_t* __restrict__ wT2,
    float* __restrict__ out) {
  __shared__ uint16_t hbuf[128 * HROW];   // 50.2 KB
  __shared__ float crdL[128][3];          // 1.5 KB (coords per row, for kk6 frag)
  __shared__ int nbrL[128];               // 0.5 KB  -> total 52.2 KB: 3 blocks/CU
  const int g = blockIdx.x, tid = threadIdx.x;
  const int wave = tid >> 6, lane = tid & 63;
  const int lrow = lane & 15, lg = lane >> 4;
  const int ns = wave;                    // n-slice: cols ns*48..+48

  #pragma unroll
  for (int ii = 0; ii < 2; ++ii) { // merge 4 sorted 16-lists for query g*8 + ii*4 + wave
    int q = ii * 4 + wave;
    int list = lane >> 4, pos = lane & 15;
    int rpos = (list & 1) ? (15 - pos) : pos;
    u64 key = keys[((size_t)g * 8 + q) * 64 + list * 16 + rpos];
    #pragma unroll
    for (int jj = 16; jj > 0; jj >>= 1) {
      u64 p = __shfl_xor(key, jj);
      bool takeMin = (((lane & jj) == 0) == ((lane & 32) == 0));
      key = (takeMin == (p < key)) ? p : key;
    }
    #pragma unroll
    for (int jj = 32; jj > 0; jj >>= 1) {
      u64 p = __shfl_xor(key, jj);
      bool takeMin = ((lane & jj) == 0);
      key = (takeMin == (p < key)) ? p : key;
    }
    if (lane < 16) nbrL[q * 16 + lane] = (int)(u32)key;
  }
  __syncthreads();

  { // h0 fill (sincos channels 0..191), 2 threads/row, static half-loops
    int r = tid >> 1, half = tid & 1;
    int grow = g * 128 + r;
    int b = grow >> 14;
    int pidx = nbrL[r];
    const float* pp = pts + ((size_t)b * NPTS + pidx) * 3;
    float c0 = pp[0], c1 = pp[1], c2 = pp[2];
    uint16_t* hrow = hbuf + r * HROW;
    if (half == 0) {
      crdL[r][0] = c0; crdL[r][1] = c1; crdL[r][2] = c2;
      #pragma unroll
      for (int jj = 0; jj < 24; ++jj) {
        const int c = jj * 4;
        uint2 pk;
        pk.x = pk2bf(h0ch(c,     c0, c1, c2), h0ch(c + 1, c0, c1, c2));
        pk.y = pk2bf(h0ch(c + 2, c0, c1, c2), h0ch(c + 3, c0, c1, c2));
        *(uint2*)(hrow + c) = pk;
      }
    } else {
      #pragma unroll
      for (int jj = 0; jj < 24; ++jj) {
        const int c = 96 + jj * 4;
        uint2 pk;
        pk.x = pk2bf(h0ch(c,     c0, c1, c2), h0ch(c + 1, c0, c1, c2));
        pk.y = pk2bf(h0ch(c + 2, c0, c1, c2), h0ch(c + 3, c0, c1, c2));
        *(uint2*)(hrow + c) = pk;
      }
    }
  }
  __syncthreads();

  // ---- gemm1 (SWAPPED operands): D1^T = wT1e-as-A x h0-as-B; kk6 B built in-reg
  f32x4 acc1[3][8] = {};
  {
    const uint16_t* wbase = wT1e + (size_t)(ns * 48 + lrow) * KP1 + lg * 8;
    uint4 anx[2][3];
    #pragma unroll
    for (int nt = 0; nt < 3; ++nt) {
      anx[0][nt] = *(const uint4*)(wbase + nt * 16 * KP1);
      anx[1][nt] = *(const uint4*)(wbase + nt * 16 * KP1 + 32);
    }
    #pragma unroll
    for (int kk = 0; kk < 7; ++kk) {
      uint4 acur[3];
      #pragma unroll
      for (int nt = 0; nt < 3; ++nt) acur[nt] = anx[kk & 1][nt];
      if (kk < 5) {
        #pragma unroll
        for (int nt = 0; nt < 3; ++nt)
          anx[kk & 1][nt] = *(const uint4*)(wbase + nt * 16 * KP1 + (kk + 2) * 32);
      }
      s16x8 bm[8];
      if (kk < 6) {
        #pragma unroll
        for (int mt = 0; mt < 8; ++mt)
          bm[mt] = __builtin_bit_cast(s16x8,
                     *(const uint4*)(hbuf + (mt * 16 + lrow) * HROW + kk * 32 + lg * 8));
      } else {
        // channels 192..223 = [c0,c1,c2,1,0...]: only lanes lg==0 carry data
        #pragma unroll
        for (int mt = 0; mt < 8; ++mt) {
          uint4 t{0, 0, 0, 0};
          if (lg == 0) {
            const float* cp = crdL[mt * 16 + lrow];
            t.x = pk2bf(cp[0], cp[1]);
            t.y = pk2bf(cp[2], 1.0f);
          }
          bm[mt] = __builtin_bit_cast(s16x8, t);
        }
      }
      #pragma unroll
      for (int nt = 0; nt < 3; ++nt)
        #pragma unroll
        for (int mt = 0; mt < 8; ++mt)
          acc1[nt][mt] = __builtin_amdgcn_mfma_f32_16x16x32_bf16(
              __builtin_bit_cast(s16x8, acur[nt]), bm[mt], acc1[nt][mt], 0, 0, 0);
    }
  }
  __syncthreads();   // all gemm1 reads of hbuf done before h1 overwrite

  { // epilogue 1: gelu (b1 folded), h1 write: 4 consecutive cols per b64 store
    #pragma unroll
    for (int nt = 0; nt < 3; ++nt) {
      #pragma unroll
      for (int mt = 0; mt < 8; ++mt) {
        uint2 pk;
        pk.x = pk2bf(gelu_f(acc1[nt][mt][0]), gelu_f(acc1[nt][mt][1]));
        pk.y = pk2bf(gelu_f(acc1[nt][mt][2]), gelu_f(acc1[nt][mt][3]));
        *(uint2*)(hbuf + (mt * 16 + lrow) * HROW + ns * 48 + nt * 16 + lg * 4) = pk;
      }
    }
  }
  __syncthreads();

  // ---- gemm2 (normal orientation): D2 = h1-as-A x wT2-as-B, 2-deep prefetch
  f32x4 acc2[8][3] = {};
  {
    const uint16_t* w2base = wT2 + (size_t)(ns * 48 + lrow) * NH + lg * 8;
    uint4 bnx[2][3];
    #pragma unroll
    for (int nt = 0; nt < 3; ++nt) {
      bnx[0][nt] = *(const uint4*)(w2base + nt * 16 * NH);
      bnx[1][nt] = *(const uint4*)(w2base + nt * 16 * NH + 32);
    }
    #pragma unroll
    for (int kk = 0; kk < 6; ++kk) {
      uint4 bcur[3];
      #pragma unroll
      for (int nt = 0; nt < 3; ++nt) bcur[nt] = bnx[kk & 1][nt];
      if (kk < 4) {
        #pragma unroll
        for (int nt = 0; nt < 3; ++nt)
          bnx[kk & 1][nt] = *(const uint4*)(w2base + nt * 16 * NH + (kk + 2) * 32);
      }
      s16x8 am[8];
      #pragma unroll
      for (int mt = 0; mt < 8; ++mt)
        am[mt] = __builtin_bit_cast(s16x8,
                   *(const uint4*)(hbuf + (mt * 16 + lrow) * HROW + kk * 32 + lg * 8));
      #pragma unroll
      for (int mt = 0; mt < 8; ++mt)
        #pragma unroll
        for (int nt = 0; nt < 3; ++nt)
          acc2[mt][nt] = __builtin_amdgcn_mfma_f32_16x16x32_bf16(
              am[mt], __builtin_bit_cast(s16x8, bcur[nt]), acc2[mt][nt], 0, 0, 0);
    }
  }

  { // epilogue 2: mean over 16 rows of each C-tile (one supernode) + b2
    #pragma unroll
    for (int mt = 0; mt < 8; ++mt) {
      #pragma unroll
      for (int nt = 0; nt < 3; ++nt) {
        float ssum = acc2[mt][nt][0] + acc2[mt][nt][1] + acc2[mt][nt][2] + acc2[mt][nt][3];
        ssum += __shfl_xor(ssum, 16);
        ssum += __shfl_xor(ssum, 32);
        if (lane < 16) {
          int col = ns * 48 + nt * 16 + lrow;
          out[(size_t)(g * 8 + mt) * NH + col] = ssum * 0.0625f + b2v[col];
        }
      }
    }
  }
}

extern "C" void kernel_launch(void* const* d_in, const int* in_sizes, int n_in,
                              void* d_out, int out_size, void* d_ws, size_t ws_size,
                              hipStream_t stream) {
  (void)in_sizes; (void)n_in; (void)out_size; (void)ws_size;
  const float* pts  = (const float*)d_in[0];
  const int*   sidx = (const int*)d_in[1];
  const float* w_in = (const float*)d_in[2];
  const float* b_in = (const float*)d_in[3];
  const float* w1   = (const float*)d_in[4];
  const float* b1   = (const float*)d_in[5];
  const float* w2   = (const float*)d_in[6];
  const float* b2   = (const float*)d_in[7];
  float* out = (float*)d_out;

  u64* keys = (u64*)d_ws;                                       // 8192*64*8 = 4 MB
  uint16_t* wT1e = (uint16_t*)((char*)d_ws + (size_t)NB * NS * 64 * 8);
  uint16_t* wT2  = wT1e + NH * KP1;

  hipLaunchKernelGGL(prep_weights, dim3(NH), dim3(64), 0, stream,
                     w_in, b_in, w1, b1, w2, wT1e, wT2);

  hipLaunchKernelGGL(knn_kernel, dim3(NB * 128), dim3(512), 0, stream,
                     pts, sidx, keys);

  hipLaunchKernelGGL(mlp_kernel, dim3(NB * NS / 8), dim3(256), 0, stream,
                     pts, keys, b2, wT1e, wT2, out);
}